// Round 1
// baseline (192.337 us; speedup 1.0000x reference)
//
#include <hip/hip_runtime.h>
#include <hip/hip_bf16.h>

#define Nn 65536
#define Ss 4

typedef short s16x8 __attribute__((ext_vector_type(8)));
typedef float f32x4 __attribute__((ext_vector_type(4)));

__device__ __forceinline__ unsigned short f2bf(float x) {
    unsigned int u = __float_as_uint(x);
    u += 0x7FFFu + ((u >> 16) & 1u);
    return (unsigned short)(u >> 16);
}

// ---------------- k_setup: best_t / best_prob / counters / C2 staging ----------------
__global__ void k_setup(const float* __restrict__ tm, const float* __restrict__ c2,
                        const float* __restrict__ C2,
                        int* counts, int* best_t, float* best_prob, float* c2v, float* C2f) {
    __shared__ int bt[4];
    int t = threadIdx.x;
    if (t < 4) {
        float m = tm[t * 4];
        int am = 0;
        for (int j = 1; j < 4; ++j) {
            float v = tm[t * 4 + j];
            if (v > m) { m = v; am = j; }   // first max wins (strict >), matches jnp.argmax
        }
        best_t[t] = am;
        bt[t] = am;
        best_prob[t] = 1.f / (1.f + expf(-m));
        counts[t] = 0;
        c2v[t] = c2[t * 4 + am];
    }
    __syncthreads();
    for (int i = t; i < 512; i += blockDim.x) {
        int s = i >> 7, h = i & 127;
        C2f[i] = C2[(s * 4 + bt[s]) * 128 + h];
    }
}

// ---------------- k_bucket: compact row indices per type, write item_prob ----------------
__global__ void k_bucket(const int* __restrict__ type_ids, const float* __restrict__ best_prob,
                         int* counts, int* buckets, float* __restrict__ out_prob) {
    int i = blockIdx.x * 256 + threadIdx.x;
    int s = type_ids[i];
    out_prob[i] = best_prob[s];
    int lane = threadIdx.x & 63;
    for (int sv = 0; sv < 4; ++sv) {
        unsigned long long m = __ballot(s == sv);
        if (m) {
            int leader = __ffsll(m) - 1;
            int cntw = __popcll(m);
            int base = 0;
            if (lane == leader) base = atomicAdd(&counts[sv], cntw);
            base = __shfl(base, leader, 64);
            if (s == sv) {
                int off = __popcll(m & ((1ull << lane) - 1ull));
                buckets[sv * Nn + base + off] = i;
            }
        }
    }
}

// ---------------- k_convert: fp32 [k][n] -> bf16 [n][k] for the 12 live matrices ----------------
__global__ void k_convert(const float* __restrict__ W1, const float* __restrict__ W2,
                          const float* __restrict__ C1, const int* __restrict__ best_t,
                          unsigned short* __restrict__ wbf) {
    int idx = blockIdx.x * 256 + threadIdx.x;   // 0 .. 196607
    int mat = idx >> 14;                        // 0..11  (s*3 + w)
    int e = idx & 16383;
    int s = mat / 3, w = mat % 3;
    int t = best_t[s];
    int row = e >> 7, col = e & 127;            // dst: [row=n][col=k]
    const float* src = (w == 0) ? W1 : (w == 1) ? W2 : C1;
    float v = src[((s * 4 + t) << 14) + col * 128 + row];
    wbf[idx] = f2bf(v);
}

// ---------------- k_main: 64 gathered rows/block, 3 MFMA GEMM phases ----------------
__global__ __launch_bounds__(256, 2) void k_main(
    const float* __restrict__ states, const float* __restrict__ scores,
    const float* __restrict__ b1g, const float* __restrict__ b2g, const float* __restrict__ c1g,
    const int* __restrict__ counts, const int* __restrict__ best_t,
    const int* __restrict__ buckets, const unsigned short* __restrict__ wbf,
    const float* __restrict__ C2f, const float* __restrict__ c2v,
    float* __restrict__ out_state, float* __restrict__ out_score)
{
    __shared__ int gIdx[64];
    __shared__ unsigned short Abuf[64 * 136];   // pitch 136: +8 bf16 pad -> 2-way banks (free)
    __shared__ unsigned short Hbuf[64 * 136];
    __shared__ unsigned short Wbuf[128 * 136];

    const int s = blockIdx.y;
    const int cnt = counts[s];
    const int rowBase = blockIdx.x << 6;
    if (rowBase >= cnt) return;
    const int valid = (cnt - rowBase < 64) ? (cnt - rowBase) : 64;
    const int t = threadIdx.x;
    const int tt = best_t[s];
    const int stIdx = s * 4 + tt;

    if (t < 64) gIdx[t] = (t < valid) ? buckets[s * Nn + rowBase + t] : -1;
    __syncthreads();

    // ---- stage A tile (gather + fp32->bf16) ----
    {
        int r = t >> 2, q = t & 3;
        int g = gIdx[r];
        unsigned short* dst = &Abuf[r * 136 + q * 32];
        if (g >= 0) {
            const float4* src = (const float4*)(states + (size_t)g * 128 + q * 32);
            #pragma unroll
            for (int i = 0; i < 8; ++i) {
                float4 v = src[i];
                ushort4 o;
                o.x = f2bf(v.x); o.y = f2bf(v.y); o.z = f2bf(v.z); o.w = f2bf(v.w);
                *(ushort4*)(dst + i * 4) = o;
            }
        } else {
            #pragma unroll
            for (int i = 0; i < 8; ++i) *(ushort4*)(dst + i * 4) = ushort4{0, 0, 0, 0};
        }
    }

    const int lane = t & 63;
    const int wv = t >> 6;          // wave 0..3 -> rows wv*16..+15
    const int m0 = wv << 4;
    const int l15 = lane & 15;
    const int quad = lane >> 4;
    const int kq = quad << 3;       // quad*8

    // stage one 128x128 bf16 weight matrix into Wbuf (pitch 136)
    auto stageW = [&](const unsigned short* src) {
        #pragma unroll
        for (int i = 0; i < 8; ++i) {
            int idx = (t + i * 256) * 8;
            int row = idx >> 7, col = idx & 127;
            s16x8 v = *(const s16x8*)(src + idx);
            *(s16x8*)(&Wbuf[row * 136 + col]) = v;
        }
    };

    // wave computes 16 rows x 128 cols: A[m][k] frag + B[n][k] frag (B pre-transposed)
    auto gemm = [&](const unsigned short* Ab, f32x4 acc[8]) {
        #pragma unroll
        for (int n = 0; n < 8; ++n) acc[n] = f32x4{0.f, 0.f, 0.f, 0.f};
        #pragma unroll
        for (int kk = 0; kk < 4; ++kk) {
            s16x8 af = *(const s16x8*)(Ab + (m0 + l15) * 136 + kk * 32 + kq);
            #pragma unroll
            for (int n = 0; n < 8; ++n) {
                s16x8 bf = *(const s16x8*)(&Wbuf[(n * 16 + l15) * 136 + kk * 32 + kq]);
                acc[n] = __builtin_amdgcn_mfma_f32_16x16x32_bf16(af, bf, acc[n], 0, 0, 0);
            }
        }
    };

    f32x4 acc[8];

    // ---- phase 1: h = relu(A @ W1 + b1) -> Hbuf (bf16) ----
    stageW(wbf + (s * 3 + 0) * 16384);
    __syncthreads();
    gemm(Abuf, acc);
    {
        const float* b1p = b1g + stIdx * 128;
        #pragma unroll
        for (int n = 0; n < 8; ++n) {
            int col = n * 16 + l15;
            float bias = b1p[col];
            #pragma unroll
            for (int r = 0; r < 4; ++r) {
                float v = fmaxf(acc[n][r] + bias, 0.f);
                Hbuf[(m0 + quad * 4 + r) * 136 + col] = f2bf(v);
            }
        }
    }
    __syncthreads();

    // ---- phase 2: y = h @ W2 + b2 -> scatter out_state ----
    stageW(wbf + (s * 3 + 1) * 16384);
    __syncthreads();
    gemm(Hbuf, acc);
    {
        int grow[4];
        #pragma unroll
        for (int r = 0; r < 4; ++r) {
            int row = m0 + quad * 4 + r;
            grow[r] = (row < valid) ? gIdx[row] : -1;
        }
        const float* b2p = b2g + stIdx * 128;
        #pragma unroll
        for (int n = 0; n < 8; ++n) {
            int col = n * 16 + l15;
            float bias = b2p[col];
            #pragma unroll
            for (int r = 0; r < 4; ++r) {
                if (grow[r] >= 0) out_state[(size_t)grow[r] * 128 + col] = acc[n][r] + bias;
            }
        }
    }
    __syncthreads();

    // ---- phase 3: hc = relu(A @ C1 + c1); cls = sigmoid(hc . C2 + c2); score = min ----
    stageW(wbf + (s * 3 + 2) * 16384);
    __syncthreads();
    gemm(Abuf, acc);
    {
        const float* c1p = c1g + stIdx * 128;
        const float* C2p = C2f + s * 128;
        float part[4] = {0.f, 0.f, 0.f, 0.f};
        #pragma unroll
        for (int n = 0; n < 8; ++n) {
            int col = n * 16 + l15;
            float cb = c1p[col];
            float cw = C2p[col];
            #pragma unroll
            for (int r = 0; r < 4; ++r) {
                float v = fmaxf(acc[n][r] + cb, 0.f);
                part[r] += v * cw;
            }
        }
        #pragma unroll
        for (int off = 1; off < 16; off <<= 1) {
            #pragma unroll
            for (int r = 0; r < 4; ++r) part[r] += __shfl_xor(part[r], off, 64);
        }
        if (l15 == 0) {
            float c2s = c2v[s];
            #pragma unroll
            for (int r = 0; r < 4; ++r) {
                int row = m0 + quad * 4 + r;
                if (row < valid) {
                    int g = gIdx[row];
                    float cls = 1.f / (1.f + expf(-(part[r] + c2s)));
                    out_score[g] = fminf(scores[g], cls);
                }
            }
        }
    }
}

extern "C" void kernel_launch(void* const* d_in, const int* in_sizes, int n_in,
                              void* d_out, int out_size, void* d_ws, size_t ws_size,
                              hipStream_t stream) {
    const float* states = (const float*)d_in[0];
    const float* scores = (const float*)d_in[1];
    const int*   type_ids = (const int*)d_in[2];
    const float* tm = (const float*)d_in[3];
    const float* W1 = (const float*)d_in[4];
    const float* b1 = (const float*)d_in[5];
    const float* W2 = (const float*)d_in[6];
    const float* b2 = (const float*)d_in[7];
    const float* C1 = (const float*)d_in[8];
    const float* c1 = (const float*)d_in[9];
    const float* C2 = (const float*)d_in[10];
    const float* c2 = (const float*)d_in[11];

    char* ws = (char*)d_ws;
    int*   counts    = (int*)(ws + 0);
    int*   best_t    = (int*)(ws + 16);
    float* best_prob = (float*)(ws + 32);
    float* c2v       = (float*)(ws + 48);
    float* C2f       = (float*)(ws + 64);        // 512 floats
    int*   buckets   = (int*)(ws + 4096);        // 4 * 65536 ints = 1 MB
    unsigned short* wbf = (unsigned short*)(ws + 1052672);  // 12 * 16384 bf16 = 384 KB

    float* out_state = (float*)d_out;                       // N*128
    float* out_score = out_state + (size_t)Nn * 128;        // N
    float* out_prob  = out_score + Nn;                      // N

    k_setup<<<1, 64, 0, stream>>>(tm, c2, C2, counts, best_t, best_prob, c2v, C2f);
    k_bucket<<<Nn / 256, 256, 0, stream>>>(type_ids, best_prob, counts, buckets, out_prob);
    k_convert<<<768, 256, 0, stream>>>(W1, W2, C1, best_t, wbf);
    k_main<<<dim3(1024, 4), 256, 0, stream>>>(states, scores, b1, b2, c1,
        counts, best_t, buckets, wbf, C2f, c2v, out_state, out_score);
}

// Round 2
// 143.269 us; speedup vs baseline: 1.3425x; 1.3425x over previous
//
#include <hip/hip_runtime.h>
#include <hip/hip_bf16.h>

#define Nn 65536

typedef short s16x8 __attribute__((ext_vector_type(8)));
typedef float f32x4 __attribute__((ext_vector_type(4)));

__device__ __forceinline__ unsigned short f2bf(float x) {
    unsigned int u = __float_as_uint(x);
    u += 0x7FFFu + ((u >> 16) & 1u);
    return (unsigned short)(u >> 16);
}

// argmax over row s of the 4x4 type_matching (first max wins, matches jnp.argmax)
__device__ __forceinline__ int best_t_for(const float* __restrict__ tm, int s, float* mOut) {
    float m = tm[s * 4];
    int am = 0;
    #pragma unroll
    for (int j = 1; j < 4; ++j) {
        float v = tm[s * 4 + j];
        if (v > m) { m = v; am = j; }
    }
    if (mOut) *mOut = m;
    return am;
}

// ---------------- k_count: per-block histogram (ballot-based) + item_prob ----------------
__global__ void k_count(const int* __restrict__ type_ids, const float* __restrict__ tm,
                        int* __restrict__ blockHist, float* __restrict__ out_prob) {
    __shared__ float prob[4];
    __shared__ int hist[4];
    const int tid = threadIdx.x;
    if (tid < 4) {
        hist[tid] = 0;
        float m;
        best_t_for(tm, tid, &m);
        prob[tid] = 1.f / (1.f + expf(-m));
    }
    __syncthreads();
    const int gid = blockIdx.x * 256 + tid;
    int4 ids = ((const int4*)type_ids)[gid];
    float4 p;
    p.x = prob[ids.x]; p.y = prob[ids.y]; p.z = prob[ids.z]; p.w = prob[ids.w];
    ((float4*)out_prob)[gid] = p;
    const int lane = tid & 63;
    int idarr[4] = {ids.x, ids.y, ids.z, ids.w};
    #pragma unroll
    for (int j = 0; j < 4; ++j) {
        #pragma unroll
        for (int sv = 0; sv < 4; ++sv) {
            unsigned long long m = __ballot(idarr[j] == sv);
            if (lane == 0 && m) atomicAdd(&hist[sv], __popcll(m));
        }
    }
    __syncthreads();
    if (tid < 4) blockHist[blockIdx.x * 4 + tid] = hist[tid];
}

// ---------------- k_scatter: deterministic partition, no global atomics ----------------
__global__ void k_scatter(const int* __restrict__ type_ids, const int* __restrict__ blockHist,
                          int* __restrict__ buckets, int* __restrict__ counts) {
    __shared__ int histAll[256];
    __shared__ int off[4];
    const int tid = threadIdx.x;
    histAll[tid] = blockHist[tid];
    __syncthreads();
    if (tid < 4) {
        int ex = 0, tot = 0;
        for (int b = 0; b < 64; ++b) {
            int v = histAll[b * 4 + tid];
            if (b < (int)blockIdx.x) ex += v;
            tot += v;
        }
        off[tid] = ex;
        if (blockIdx.x == 0) counts[tid] = tot;
    }
    __syncthreads();
    const int gid = blockIdx.x * 256 + tid;
    int4 ids = ((const int4*)type_ids)[gid];
    const int base = gid * 4;
    int idarr[4] = {ids.x, ids.y, ids.z, ids.w};
    #pragma unroll
    for (int j = 0; j < 4; ++j) {
        int sv = idarr[j];
        int pos = atomicAdd(&off[sv], 1);     // LDS atomic: cheap, block-local
        buckets[sv * Nn + pos] = base + j;
    }
}

// ---------------- k_convert: fp32 [k][n] -> bf16 [n][k] for the 12 live matrices ----------------
__global__ void k_convert(const float* __restrict__ W1, const float* __restrict__ W2,
                          const float* __restrict__ C1, const float* __restrict__ tm,
                          unsigned short* __restrict__ wbf) {
    int idx = blockIdx.x * 256 + threadIdx.x;   // 0 .. 196607
    int mat = idx >> 14;                        // 0..11  (s*3 + w)
    int e = idx & 16383;
    int s = mat / 3, w = mat % 3;
    int t = best_t_for(tm, s, nullptr);
    int row = e >> 7, col = e & 127;            // dst: [row=n][col=k]
    const float* src = (w == 0) ? W1 : (w == 1) ? W2 : C1;
    float v = src[((s * 4 + t) << 14) + col * 128 + row];
    wbf[idx] = f2bf(v);
}

// ---------------- k_main: 64 gathered rows/block, 3 MFMA GEMM phases ----------------
__global__ __launch_bounds__(256, 2) void k_main(
    const float* __restrict__ states, const float* __restrict__ scores,
    const float* __restrict__ b1g, const float* __restrict__ b2g, const float* __restrict__ c1g,
    const float* __restrict__ tm, const float* __restrict__ C2, const float* __restrict__ c2,
    const int* __restrict__ counts, const int* __restrict__ buckets,
    const unsigned short* __restrict__ wbf,
    float* __restrict__ out_state, float* __restrict__ out_score)
{
    __shared__ int gIdx[64];
    __shared__ float C2s[128];
    __shared__ unsigned short Abuf[64 * 136];   // pitch 136: +8 bf16 pad -> 2-way banks (free)
    __shared__ unsigned short Hbuf[64 * 136];
    __shared__ unsigned short Wbuf[128 * 136];

    const int s = blockIdx.y;
    const int cnt = counts[s];
    const int rowBase = blockIdx.x << 6;
    if (rowBase >= cnt) return;
    const int valid = (cnt - rowBase < 64) ? (cnt - rowBase) : 64;
    const int t = threadIdx.x;
    const int tt = best_t_for(tm, s, nullptr);
    const int stIdx = s * 4 + tt;

    if (t < 64) gIdx[t] = (t < valid) ? buckets[s * Nn + rowBase + t] : -1;
    if (t >= 128 && t < 256) C2s[t - 128] = C2[stIdx * 128 + (t - 128)];
    __syncthreads();

    // ---- stage A tile (gather + fp32->bf16) ----
    {
        int r = t >> 2, q = t & 3;
        int g = gIdx[r];
        unsigned short* dst = &Abuf[r * 136 + q * 32];
        if (g >= 0) {
            const float4* src = (const float4*)(states + (size_t)g * 128 + q * 32);
            #pragma unroll
            for (int i = 0; i < 8; ++i) {
                float4 v = src[i];
                ushort4 o;
                o.x = f2bf(v.x); o.y = f2bf(v.y); o.z = f2bf(v.z); o.w = f2bf(v.w);
                *(ushort4*)(dst + i * 4) = o;
            }
        } else {
            #pragma unroll
            for (int i = 0; i < 8; ++i) *(ushort4*)(dst + i * 4) = ushort4{0, 0, 0, 0};
        }
    }

    const int lane = t & 63;
    const int wv = t >> 6;          // wave 0..3 -> rows wv*16..+15
    const int m0 = wv << 4;
    const int l15 = lane & 15;
    const int quad = lane >> 4;
    const int kq = quad << 3;       // quad*8

    // stage one 128x128 bf16 weight matrix into Wbuf (pitch 136)
    auto stageW = [&](const unsigned short* src) {
        #pragma unroll
        for (int i = 0; i < 8; ++i) {
            int idx = (t + i * 256) * 8;
            int row = idx >> 7, col = idx & 127;
            s16x8 v = *(const s16x8*)(src + idx);
            *(s16x8*)(&Wbuf[row * 136 + col]) = v;
        }
    };

    // wave computes 16 rows x 128 cols: A[m][k] frag + B[n][k] frag (B pre-transposed)
    auto gemm = [&](const unsigned short* Ab, f32x4 acc[8]) {
        #pragma unroll
        for (int n = 0; n < 8; ++n) acc[n] = f32x4{0.f, 0.f, 0.f, 0.f};
        #pragma unroll
        for (int kk = 0; kk < 4; ++kk) {
            s16x8 af = *(const s16x8*)(Ab + (m0 + l15) * 136 + kk * 32 + kq);
            #pragma unroll
            for (int n = 0; n < 8; ++n) {
                s16x8 bf = *(const s16x8*)(&Wbuf[(n * 16 + l15) * 136 + kk * 32 + kq]);
                acc[n] = __builtin_amdgcn_mfma_f32_16x16x32_bf16(af, bf, acc[n], 0, 0, 0);
            }
        }
    };

    f32x4 acc[8];

    // ---- phase 1: h = relu(A @ W1 + b1) -> Hbuf (bf16) ----
    stageW(wbf + (s * 3 + 0) * 16384);
    __syncthreads();
    gemm(Abuf, acc);
    {
        const float* b1p = b1g + stIdx * 128;
        #pragma unroll
        for (int n = 0; n < 8; ++n) {
            int col = n * 16 + l15;
            float bias = b1p[col];
            #pragma unroll
            for (int r = 0; r < 4; ++r) {
                float v = fmaxf(acc[n][r] + bias, 0.f);
                Hbuf[(m0 + quad * 4 + r) * 136 + col] = f2bf(v);
            }
        }
    }
    __syncthreads();

    // ---- phase 2: y = h @ W2 + b2 -> scatter out_state ----
    stageW(wbf + (s * 3 + 1) * 16384);
    __syncthreads();
    gemm(Hbuf, acc);
    {
        int grow[4];
        #pragma unroll
        for (int r = 0; r < 4; ++r) {
            int row = m0 + quad * 4 + r;
            grow[r] = (row < valid) ? gIdx[row] : -1;
        }
        const float* b2p = b2g + stIdx * 128;
        #pragma unroll
        for (int n = 0; n < 8; ++n) {
            int col = n * 16 + l15;
            float bias = b2p[col];
            #pragma unroll
            for (int r = 0; r < 4; ++r) {
                if (grow[r] >= 0) out_state[(size_t)grow[r] * 128 + col] = acc[n][r] + bias;
            }
        }
    }
    __syncthreads();

    // ---- phase 3: hc = relu(A @ C1 + c1); cls = sigmoid(hc . C2 + c2); score = min ----
    stageW(wbf + (s * 3 + 2) * 16384);
    __syncthreads();
    gemm(Abuf, acc);
    {
        const float* c1p = c1g + stIdx * 128;
        float part[4] = {0.f, 0.f, 0.f, 0.f};
        #pragma unroll
        for (int n = 0; n < 8; ++n) {
            int col = n * 16 + l15;
            float cb = c1p[col];
            float cw = C2s[col];
            #pragma unroll
            for (int r = 0; r < 4; ++r) {
                float v = fmaxf(acc[n][r] + cb, 0.f);
                part[r] += v * cw;
            }
        }
        #pragma unroll
        for (int off = 1; off < 16; off <<= 1) {
            #pragma unroll
            for (int r = 0; r < 4; ++r) part[r] += __shfl_xor(part[r], off, 64);
        }
        if (l15 == 0) {
            float c2s = c2[stIdx];
            #pragma unroll
            for (int r = 0; r < 4; ++r) {
                int row = m0 + quad * 4 + r;
                if (row < valid) {
                    int g = gIdx[row];
                    float cls = 1.f / (1.f + expf(-(part[r] + c2s)));
                    out_score[g] = fminf(scores[g], cls);
                }
            }
        }
    }
}

extern "C" void kernel_launch(void* const* d_in, const int* in_sizes, int n_in,
                              void* d_out, int out_size, void* d_ws, size_t ws_size,
                              hipStream_t stream) {
    const float* states = (const float*)d_in[0];
    const float* scores = (const float*)d_in[1];
    const int*   type_ids = (const int*)d_in[2];
    const float* tm = (const float*)d_in[3];
    const float* W1 = (const float*)d_in[4];
    const float* b1 = (const float*)d_in[5];
    const float* W2 = (const float*)d_in[6];
    const float* b2 = (const float*)d_in[7];
    const float* C1 = (const float*)d_in[8];
    const float* c1 = (const float*)d_in[9];
    const float* C2 = (const float*)d_in[10];
    const float* c2 = (const float*)d_in[11];

    char* ws = (char*)d_ws;
    int*   counts    = (int*)(ws + 0);           // 4 ints
    int*   blockHist = (int*)(ws + 64);          // 64*4 ints = 1 KB
    int*   buckets   = (int*)(ws + 4096);        // 4 * 65536 ints = 1 MB
    unsigned short* wbf = (unsigned short*)(ws + 1052672);  // 12 * 16384 bf16 = 384 KB

    float* out_state = (float*)d_out;                       // N*128
    float* out_score = out_state + (size_t)Nn * 128;        // N
    float* out_prob  = out_score + Nn;                      // N

    k_count<<<64, 256, 0, stream>>>(type_ids, tm, blockHist, out_prob);
    k_scatter<<<64, 256, 0, stream>>>(type_ids, blockHist, buckets, counts);
    k_convert<<<768, 256, 0, stream>>>(W1, W2, C1, tm, wbf);
    k_main<<<dim3(1024, 4), 256, 0, stream>>>(states, scores, b1, b2, c1,
        tm, C2, c2, counts, buckets, wbf, out_state, out_score);
}

// Round 3
// 131.911 us; speedup vs baseline: 1.4581x; 1.0861x over previous
//
#include <hip/hip_runtime.h>
#include <math.h>

#define Nn 65536

typedef short s16x8 __attribute__((ext_vector_type(8)));
typedef float f32x4 __attribute__((ext_vector_type(4)));
typedef unsigned int u32;

__device__ __forceinline__ unsigned short f2bf(float x) {
    u32 u = __float_as_uint(x);
    u += 0x7FFFu + ((u >> 16) & 1u);
    return (unsigned short)(u >> 16);
}

// argmax over row s of the 4x4 type_matching (first max wins, matches jnp.argmax)
__device__ __forceinline__ int best_t_for(const float* __restrict__ tm, int s, float* mOut) {
    float m = tm[s * 4];
    int am = 0;
#pragma unroll
    for (int j = 1; j < 4; ++j) {
        float v = tm[s * 4 + j];
        if (v > m) { m = v; am = j; }
    }
    if (mOut) *mOut = m;
    return am;
}

// async global->LDS, 16B per lane; LDS dest must be wave-uniform base + lane*16
#define GLDS16(g, l) __builtin_amdgcn_global_load_lds( \
    (const __attribute__((address_space(1))) u32*)(g), \
    (__attribute__((address_space(3))) u32*)(l), 16, 0, 0)

// ================= k_prep: blocks 0-63 partition, blocks 64-159 weight convert =================
__global__ void k_prep(const int* __restrict__ type_ids, const float* __restrict__ tm,
                       const float* __restrict__ W1, const float* __restrict__ W2,
                       const float* __restrict__ C1,
                       int* __restrict__ counts, int* __restrict__ buckets,
                       unsigned short* __restrict__ wbf, float* __restrict__ out_prob) {
    const int tid = threadIdx.x;
    if (blockIdx.x < 64) {
        // ---- partition: per-block histogram + one global atomic per type ----
        __shared__ int hist[4];
        __shared__ int off[4];
        __shared__ float prob[4];
        if (tid < 4) {
            hist[tid] = 0;
            float m;
            best_t_for(tm, tid, &m);
            prob[tid] = 1.f / (1.f + expf(-m));
        }
        __syncthreads();
        const int gid = blockIdx.x * 256 + tid;
        int4 ids = ((const int4*)type_ids)[gid];
        float4 p;
        p.x = prob[ids.x]; p.y = prob[ids.y]; p.z = prob[ids.z]; p.w = prob[ids.w];
        ((float4*)out_prob)[gid] = p;
        const int lane = tid & 63;
        int idarr[4] = {ids.x, ids.y, ids.z, ids.w};
#pragma unroll
        for (int j = 0; j < 4; ++j) {
#pragma unroll
            for (int sv = 0; sv < 4; ++sv) {
                unsigned long long m = __ballot(idarr[j] == sv);
                if (lane == 0 && m) atomicAdd(&hist[sv], __popcll(m));
            }
        }
        __syncthreads();
        if (tid < 4) off[tid] = atomicAdd(&counts[tid], hist[tid]);  // contiguous reservation
        __syncthreads();
        const int base = gid * 4;
#pragma unroll
        for (int j = 0; j < 4; ++j) {
            int sv = idarr[j];
            int pos = atomicAdd(&off[sv], 1);   // LDS atomic, block-local
            buckets[sv * Nn + pos] = base + j;
        }
    } else {
        // ---- weight convert: fp32 [D][H] -> bf16 fragment-linear for 12 live matrices ----
        // unit u: mat = s*3+w (2048 units each); frag f = kk*8+n8; lane; 8 elems/unit
        int u = (blockIdx.x - 64) * 256 + tid;      // 0..24575
        int mat = u >> 11;
        int rr = u & 2047;
        int f = rr >> 6, lane = rr & 63;
        int kk = f >> 3, n8 = f & 7;
        int q = lane >> 4, l15 = lane & 15;
        int sm = mat / 3, w = mat - sm * 3;
        int t = best_t_for(tm, sm, nullptr);
        const float* src = (w == 0) ? W1 : (w == 1) ? W2 : C1;
        const float* sp = src + (((sm * 4 + t) << 14) + n8 * 16 + l15);
        int k0 = kk * 32 + q * 8;
        s16x8 o;
#pragma unroll
        for (int j = 0; j < 8; ++j) o[j] = (short)f2bf(sp[(k0 + j) * 128]);
        *(s16x8*)(wbf + (size_t)u * 8) = o;
    }
}

// ================= k_main: persistent weight-resident blocks, 64-row tiles =================
__global__ __launch_bounds__(256, 1) void k_main(
    const float* __restrict__ states, const float* __restrict__ scores,
    const float* __restrict__ b1g, const float* __restrict__ b2g, const float* __restrict__ c1g,
    const float* __restrict__ tm, const float* __restrict__ C2, const float* __restrict__ c2,
    const int* __restrict__ counts, const int* __restrict__ buckets,
    const unsigned short* __restrict__ wbf,
    float* __restrict__ out_state, float* __restrict__ out_score)
{
    __shared__ unsigned short Wlds[3 * 16384];        // 96 KB, fragment-linear
    __shared__ unsigned short Abuf[2][64 * 136];      // 34 KB, pitch 136
    __shared__ unsigned short Hbuf[64 * 136];         // 17 KB
    __shared__ int gIdxLds[2][64];
    __shared__ float C2s[128];

    const int s = blockIdx.y;
    const int bx = blockIdx.x;
    const int cnt = counts[s];
    const int ntiles = (cnt + 63) >> 6;
    if (bx >= ntiles) return;
    const int t = threadIdx.x;
    const int tt = best_t_for(tm, s, nullptr);
    const int stIdx = s * 4 + tt;

    // ---- stage all 3 weight matrices (96 KB) once, async direct-to-LDS ----
    {
        const unsigned short* src = wbf + (size_t)s * 3 * 16384;
#pragma unroll
        for (int i = 0; i < 24; ++i) {
            GLDS16(src + t * 8 + i * 2048, Wlds + t * 8 + i * 2048);
        }
    }
    if (t >= 128) C2s[t - 128] = C2[stIdx * 128 + (t - 128)];

    const int lane = t & 63;
    const int m0 = (t >> 6) << 4;     // wave's 16-row slice
    const int l15 = lane & 15;
    const int quad = lane >> 4;
    const int kq = quad << 3;
    const int myRow = t >> 2;         // A-staging: 4 threads per row
    const int q4 = t & 3;

    const int* bkt = buckets + s * Nn;

    // ---- prologue: stage A for tile0 = bx ----
    {
        int gr = bx * 64 + myRow;
        int rIdxC = (gr < cnt) ? bkt[gr] : -1;
        if ((t & 3) == 0) gIdxLds[0][myRow] = rIdxC;
        unsigned short* dst = &Abuf[0][myRow * 136 + q4 * 32];
        if (rIdxC >= 0) {
            const float4* sp = (const float4*)(states + (size_t)rIdxC * 128 + q4 * 32);
            float4 pf0[8];
#pragma unroll
            for (int i = 0; i < 8; ++i) pf0[i] = sp[i];
#pragma unroll
            for (int i = 0; i < 8; ++i) {
                ushort4 o;
                o.x = f2bf(pf0[i].x); o.y = f2bf(pf0[i].y);
                o.z = f2bf(pf0[i].z); o.w = f2bf(pf0[i].w);
                *(ushort4*)(dst + i * 4) = o;
            }
        } else {
#pragma unroll
            for (int i = 0; i < 8; ++i) *(ushort4*)(dst + i * 4) = ushort4{0, 0, 0, 0};
        }
    }
    int rIdxN = -1;
    if (bx + 64 < ntiles) {
        int gr = (bx + 64) * 64 + myRow;
        rIdxN = (gr < cnt) ? bkt[gr] : -1;
    }
    __syncthreads();   // drains weight global_load_lds + A0/gIdx LDS writes

    // B-fragments from fragment-linear W: lane-contiguous, conflict-free ds_read_b128
    auto gemm = [&](const unsigned short* Ab, const unsigned short* Wm, f32x4 acc[8]) {
#pragma unroll
        for (int n = 0; n < 8; ++n) acc[n] = f32x4{0.f, 0.f, 0.f, 0.f};
#pragma unroll
        for (int kk = 0; kk < 4; ++kk) {
            s16x8 af = *(const s16x8*)(Ab + (m0 + l15) * 136 + kk * 32 + kq);
#pragma unroll
            for (int n = 0; n < 8; ++n) {
                s16x8 bf = *(const s16x8*)(Wm + (size_t)((kk * 8 + n) * 64 + lane) * 8);
                acc[n] = __builtin_amdgcn_mfma_f32_16x16x32_bf16(af, bf, acc[n], 0, 0, 0);
            }
        }
    };

    f32x4 acc[8];
    int cur = 0;
    for (int tile = bx; tile < ntiles; tile += 64, cur ^= 1) {
        const int nxt = cur ^ 1;
        const bool hasNext = (tile + 64) < ntiles;

        // ---- phase 1: h = relu(A@W1 + b1) -> Hbuf ----
        gemm(Abuf[cur], Wlds, acc);
        {
            const float* b1p = b1g + stIdx * 128;
#pragma unroll
            for (int n = 0; n < 8; ++n) {
                int col = n * 16 + l15;
                float bias = b1p[col];
#pragma unroll
                for (int r = 0; r < 4; ++r) {
                    float v = fmaxf(acc[n][r] + bias, 0.f);
                    Hbuf[(m0 + quad * 4 + r) * 136 + col] = f2bf(v);
                }
            }
        }
        if ((t & 3) == 0) gIdxLds[nxt][myRow] = rIdxN;
        __syncthreads();   // H visible

        // ---- prefetch next tile's A into registers (overlaps gemm2/gemm3) ----
        float4 pf[8];
        if (hasNext && rIdxN >= 0) {
            const float4* sp = (const float4*)(states + (size_t)rIdxN * 128 + q4 * 32);
#pragma unroll
            for (int i = 0; i < 8; ++i) pf[i] = sp[i];
        }
        int rIdxN2 = -1;
        if (tile + 128 < ntiles) {
            int gr = (tile + 128) * 64 + myRow;
            rIdxN2 = (gr < cnt) ? bkt[gr] : -1;
        }

        // ---- phase 2: y = h@W2 + b2 -> scatter out_state ----
        gemm(Hbuf, Wlds + 16384, acc);
        {
            const float* b2p = b2g + stIdx * 128;
            int grow[4];
#pragma unroll
            for (int r = 0; r < 4; ++r) grow[r] = gIdxLds[cur][m0 + quad * 4 + r];
#pragma unroll
            for (int n = 0; n < 8; ++n) {
                int col = n * 16 + l15;
                float bias = b2p[col];
#pragma unroll
                for (int r = 0; r < 4; ++r) {
                    if (grow[r] >= 0) out_state[(size_t)grow[r] * 128 + col] = acc[n][r] + bias;
                }
            }
        }

        // ---- phase 3: classifier ----
        gemm(Abuf[cur], Wlds + 2 * 16384, acc);
        {
            const float* c1p = c1g + stIdx * 128;
            float part[4] = {0.f, 0.f, 0.f, 0.f};
#pragma unroll
            for (int n = 0; n < 8; ++n) {
                int col = n * 16 + l15;
                float cb = c1p[col];
                float cw = C2s[col];
#pragma unroll
                for (int r = 0; r < 4; ++r) {
                    float v = fmaxf(acc[n][r] + cb, 0.f);
                    part[r] += v * cw;
                }
            }
#pragma unroll
            for (int off = 1; off < 16; off <<= 1) {
#pragma unroll
                for (int r = 0; r < 4; ++r) part[r] += __shfl_xor(part[r], off, 64);
            }
            if (l15 == 0) {
                float c2s = c2[stIdx];
#pragma unroll
                for (int r = 0; r < 4; ++r) {
                    int g = gIdxLds[cur][m0 + quad * 4 + r];
                    if (g >= 0) {
                        float cls = 1.f / (1.f + expf(-(part[r] + c2s)));
                        out_score[g] = fminf(scores[g], cls);
                    }
                }
            }
        }

        // ---- write prefetched A into Abuf[nxt] ----
        if (hasNext) {
            unsigned short* dst = &Abuf[nxt][myRow * 136 + q4 * 32];
            if (rIdxN >= 0) {
#pragma unroll
                for (int i = 0; i < 8; ++i) {
                    ushort4 o;
                    o.x = f2bf(pf[i].x); o.y = f2bf(pf[i].y);
                    o.z = f2bf(pf[i].z); o.w = f2bf(pf[i].w);
                    *(ushort4*)(dst + i * 4) = o;
                }
            } else {
#pragma unroll
                for (int i = 0; i < 8; ++i) *(ushort4*)(dst + i * 4) = ushort4{0, 0, 0, 0};
            }
        }
        rIdxN = rIdxN2;
        __syncthreads();   // A[nxt] visible; all reads of H / A[cur] / gIdx[cur] done
    }
}

extern "C" void kernel_launch(void* const* d_in, const int* in_sizes, int n_in,
                              void* d_out, int out_size, void* d_ws, size_t ws_size,
                              hipStream_t stream) {
    const float* states = (const float*)d_in[0];
    const float* scores = (const float*)d_in[1];
    const int*   type_ids = (const int*)d_in[2];
    const float* tm = (const float*)d_in[3];
    const float* W1 = (const float*)d_in[4];
    const float* b1 = (const float*)d_in[5];
    const float* W2 = (const float*)d_in[6];
    const float* b2 = (const float*)d_in[7];
    const float* C1 = (const float*)d_in[8];
    const float* c1 = (const float*)d_in[9];
    const float* C2 = (const float*)d_in[10];
    const float* c2 = (const float*)d_in[11];

    char* ws = (char*)d_ws;
    int*   counts  = (int*)(ws + 0);                        // 4 ints
    int*   buckets = (int*)(ws + 4096);                     // 4 * 65536 ints = 1 MB
    unsigned short* wbf = (unsigned short*)(ws + 1052672);  // 12 * 16384 bf16 = 384 KB (frag-linear)

    float* out_state = (float*)d_out;                       // N*128
    float* out_score = out_state + (size_t)Nn * 128;        // N
    float* out_prob  = out_score + Nn;                      // N

    hipMemsetAsync(counts, 0, 16, stream);
    k_prep<<<160, 256, 0, stream>>>(type_ids, tm, W1, W2, C1, counts, buckets, wbf, out_prob);
    k_main<<<dim3(64, 4), 256, 0, stream>>>(states, scores, b1, b2, c1,
        tm, C2, c2, counts, buckets, wbf, out_state, out_score);
}

// Round 4
// 123.276 us; speedup vs baseline: 1.5602x; 1.0700x over previous
//
#include <hip/hip_runtime.h>
#include <math.h>

#define Nn 65536

typedef short s16x8 __attribute__((ext_vector_type(8)));
typedef float f32x4 __attribute__((ext_vector_type(4)));
typedef unsigned int u32;

__device__ __forceinline__ unsigned short f2bf(float x) {
    u32 u = __float_as_uint(x);
    u += 0x7FFFu + ((u >> 16) & 1u);
    return (unsigned short)(u >> 16);
}

// argmax over row s of the 4x4 type_matching (first max wins, matches jnp.argmax)
__device__ __forceinline__ int best_t_for(const float* __restrict__ tm, int s, float* mOut) {
    float m = tm[s * 4];
    int am = 0;
#pragma unroll
    for (int j = 1; j < 4; ++j) {
        float v = tm[s * 4 + j];
        if (v > m) { m = v; am = j; }
    }
    if (mOut) *mOut = m;
    return am;
}

// ================= k_prep: blocks 0-63 partition, blocks 64-159 weight convert =================
__global__ void k_prep(const int* __restrict__ type_ids, const float* __restrict__ tm,
                       const float* __restrict__ W1, const float* __restrict__ W2,
                       const float* __restrict__ C1,
                       int* __restrict__ counts, int* __restrict__ buckets,
                       unsigned short* __restrict__ wbf, float* __restrict__ out_prob) {
    const int tid = threadIdx.x;
    if (blockIdx.x < 64) {
        __shared__ int hist[4];
        __shared__ int off[4];
        __shared__ float prob[4];
        if (tid < 4) {
            hist[tid] = 0;
            float m;
            best_t_for(tm, tid, &m);
            prob[tid] = 1.f / (1.f + expf(-m));
        }
        __syncthreads();
        const int gid = blockIdx.x * 256 + tid;
        int4 ids = ((const int4*)type_ids)[gid];
        float4 p;
        p.x = prob[ids.x]; p.y = prob[ids.y]; p.z = prob[ids.z]; p.w = prob[ids.w];
        ((float4*)out_prob)[gid] = p;
        const int lane = tid & 63;
        int idarr[4] = {ids.x, ids.y, ids.z, ids.w};
#pragma unroll
        for (int j = 0; j < 4; ++j) {
#pragma unroll
            for (int sv = 0; sv < 4; ++sv) {
                unsigned long long m = __ballot(idarr[j] == sv);
                if (lane == 0 && m) atomicAdd(&hist[sv], __popcll(m));
            }
        }
        __syncthreads();
        if (tid < 4) off[tid] = atomicAdd(&counts[tid], hist[tid]);  // contiguous reservation
        __syncthreads();
        const int base = gid * 4;
#pragma unroll
        for (int j = 0; j < 4; ++j) {
            int sv = idarr[j];
            int pos = atomicAdd(&off[sv], 1);   // LDS atomic, block-local
            buckets[sv * Nn + pos] = base + j;
        }
    } else {
        // weight convert: fp32 [D][H] -> bf16 fragment-linear for 12 live matrices
        int u = (blockIdx.x - 64) * 256 + tid;      // 0..24575
        int mat = u >> 11;
        int rr = u & 2047;
        int f = rr >> 6, lane = rr & 63;
        int kk = f >> 3, n8 = f & 7;
        int q = lane >> 4, l15 = lane & 15;
        int sm = mat / 3, w = mat - sm * 3;
        int t = best_t_for(tm, sm, nullptr);
        const float* src = (w == 0) ? W1 : (w == 1) ? W2 : C1;
        const float* sp = src + (((sm * 4 + t) << 14) + n8 * 16 + l15);
        int k0 = kk * 32 + q * 8;
        s16x8 o;
#pragma unroll
        for (int j = 0; j < 8; ++j) o[j] = (short)f2bf(sp[(k0 + j) * 128]);
        *(s16x8*)(wbf + (size_t)u * 8) = o;
    }
}

// ================= k_main: register-held weights, n-sliced waves, swizzled LDS =================
// A/H layout: row*128 + ((col + (row&15)*8) & 127)  -- pad-free, conflict-free for b128 frags
__global__ __launch_bounds__(256, 2) void k_main(
    const float* __restrict__ states, const float* __restrict__ scores,
    const float* __restrict__ b1g, const float* __restrict__ b2g, const float* __restrict__ c1g,
    const float* __restrict__ tm, const float* __restrict__ C2, const float* __restrict__ c2,
    const int* __restrict__ counts, const int* __restrict__ buckets,
    const unsigned short* __restrict__ wbf,
    float* __restrict__ out_state, float* __restrict__ out_score)
{
    __shared__ __align__(16) unsigned short Abuf[2][64 * 128];  // 2 x 16 KB
    __shared__ __align__(16) unsigned short Hbuf[64 * 128];     // 16 KB
    __shared__ int gIdxLds[2][64];
    __shared__ float scoreLds[2][64];
    __shared__ float pLds[4][64];
    __shared__ float C2s[128];

    const int s = blockIdx.y;
    const int cnt = counts[s];
    const int ntiles = (cnt + 63) >> 6;
    const int bx = blockIdx.x;
    if (bx >= ntiles) return;
    const int t = threadIdx.x;
    const int tt = best_t_for(tm, s, nullptr);
    const int stIdx = s * 4 + tt;

    const int lane = t & 63;
    const int wv = t >> 6;           // wave -> 32-col slice (n-groups 2wv, 2wv+1)
    const int l15 = lane & 15;
    const int quad = lane >> 4;
    const int myRow = t >> 2;        // A staging: 4 threads per row
    const int q4 = t & 3;

    // ---- all 3 weight matrices' fragments for this wave's col-slice -> VGPRs ----
    s16x8 wf[3][4][2];
    {
        const unsigned short* wb = wbf + (size_t)s * 3 * 16384;
#pragma unroll
        for (int m = 0; m < 3; ++m)
#pragma unroll
            for (int kk = 0; kk < 4; ++kk)
#pragma unroll
                for (int nn = 0; nn < 2; ++nn)
                    wf[m][kk][nn] = *(const s16x8*)(wb + m * 16384 +
                        (size_t)((kk * 8 + (wv * 2 + nn)) * 64 + lane) * 8);
    }
    if (t >= 128) C2s[t - 128] = C2[stIdx * 128 + (t - 128)];

    // hoisted per-lane bias/weight constants
    float b1v[2], b2v[2], c1v[2];
#pragma unroll
    for (int nn = 0; nn < 2; ++nn) {
        int col = (wv * 2 + nn) * 16 + l15;
        b1v[nn] = b1g[stIdx * 128 + col];
        b2v[nn] = b2g[stIdx * 128 + col];
        c1v[nn] = c1g[stIdx * 128 + col];
    }
    const float c2s = c2[stIdx];

    const int* bkt = buckets + s * Nn;

    // ---- prologue: stage tile0 ----
    {
        int gr = bx * 64 + myRow;
        int g = (gr < cnt) ? bkt[gr] : -1;
        if (q4 == 0) {
            gIdxLds[0][myRow] = g;
            scoreLds[0][myRow] = (g >= 0) ? scores[g] : 0.f;
        }
        unsigned short* dstRow = &Abuf[0][myRow * 128];
        const int rot = (myRow & 15) << 3;
        if (g >= 0) {
            const float4* sp = (const float4*)(states + (size_t)g * 128 + q4 * 32);
            float4 v[8];
#pragma unroll
            for (int i = 0; i < 8; ++i) v[i] = sp[i];
#pragma unroll
            for (int i = 0; i < 8; ++i) {
                int col = (q4 * 32 + i * 4 + rot) & 127;
                ushort4 o;
                o.x = f2bf(v[i].x); o.y = f2bf(v[i].y);
                o.z = f2bf(v[i].z); o.w = f2bf(v[i].w);
                *(ushort4*)(dstRow + col) = o;
            }
        } else {
#pragma unroll
            for (int i = 0; i < 8; ++i) {
                int col = (q4 * 32 + i * 4 + rot) & 127;
                *(ushort4*)(dstRow + col) = ushort4{0, 0, 0, 0};
            }
        }
    }
    int rIdxN = -1;
    if (bx + 128 < ntiles) {
        int gr = (bx + 128) * 64 + myRow;
        rIdxN = (gr < cnt) ? bkt[gr] : -1;
    }
    __syncthreads();

    // gemm: A-frags from swizzled LDS, B-frags from registers (wf[wm])
    auto gemm = [&](const unsigned short* Ab, int wm, f32x4 acc[4][2]) {
#pragma unroll
        for (int mg = 0; mg < 4; ++mg)
#pragma unroll
            for (int nn = 0; nn < 2; ++nn) acc[mg][nn] = f32x4{0.f, 0.f, 0.f, 0.f};
#pragma unroll
        for (int kk = 0; kk < 4; ++kk) {
            const int colsw = (kk * 32 + quad * 8 + l15 * 8) & 127;  // row&15 == l15
            s16x8 af[4];
#pragma unroll
            for (int mg = 0; mg < 4; ++mg)
                af[mg] = *(const s16x8*)(Ab + (mg * 16 + l15) * 128 + colsw);
#pragma unroll
            for (int mg = 0; mg < 4; ++mg)
#pragma unroll
                for (int nn = 0; nn < 2; ++nn)
                    acc[mg][nn] = __builtin_amdgcn_mfma_f32_16x16x32_bf16(
                        af[mg], wf[wm][kk][nn], acc[mg][nn], 0, 0, 0);
        }
    };

    f32x4 acc[4][2];
    int cur = 0;
    for (int tile = bx; tile < ntiles; tile += 128, cur ^= 1) {
        const int nxt = cur ^ 1;
        const bool hasNext = (tile + 128) < ntiles;

        // ---- phase 1: h = relu(A@W1 + b1) -> Hbuf (swizzled) ----
        gemm(Abuf[cur], 0, acc);
#pragma unroll
        for (int mg = 0; mg < 4; ++mg)
#pragma unroll
            for (int nn = 0; nn < 2; ++nn) {
                int col = (wv * 2 + nn) * 16 + l15;
#pragma unroll
                for (int r = 0; r < 4; ++r) {
                    int row = mg * 16 + quad * 4 + r;
                    float v = fmaxf(acc[mg][nn][r] + b1v[nn], 0.f);
                    Hbuf[row * 128 + ((col + ((row & 15) << 3)) & 127)] = f2bf(v);
                }
            }
        if (q4 == 0) gIdxLds[nxt][myRow] = rIdxN;
        __syncthreads();

        // ---- prefetch next tile's A + score (overlaps gemm2/3) ----
        float4 pf[8];
        float scN = 0.f;
        if (hasNext && rIdxN >= 0) {
            const float4* sp = (const float4*)(states + (size_t)rIdxN * 128 + q4 * 32);
#pragma unroll
            for (int i = 0; i < 8; ++i) pf[i] = sp[i];
            scN = scores[rIdxN];
        }
        int rIdxN2 = -1;
        if (tile + 256 < ntiles) {
            int gr = (tile + 256) * 64 + myRow;
            rIdxN2 = (gr < cnt) ? bkt[gr] : -1;
        }

        // ---- phase 2: y = h@W2 + b2 -> scatter out_state ----
        gemm(Hbuf, 1, acc);
#pragma unroll
        for (int mg = 0; mg < 4; ++mg) {
            int gr4[4];
#pragma unroll
            for (int r = 0; r < 4; ++r) gr4[r] = gIdxLds[cur][mg * 16 + quad * 4 + r];
#pragma unroll
            for (int nn = 0; nn < 2; ++nn) {
                int col = (wv * 2 + nn) * 16 + l15;
                float bias = b2v[nn];
#pragma unroll
                for (int r = 0; r < 4; ++r)
                    if (gr4[r] >= 0) out_state[(size_t)gr4[r] * 128 + col] = acc[mg][nn][r] + bias;
            }
        }

        // ---- phase 3: classifier partials (this wave's 32 cols) ----
        gemm(Abuf[cur], 2, acc);
        {
            float part[4][4];
#pragma unroll
            for (int mg = 0; mg < 4; ++mg)
#pragma unroll
                for (int r = 0; r < 4; ++r) part[mg][r] = 0.f;
#pragma unroll
            for (int nn = 0; nn < 2; ++nn) {
                int col = (wv * 2 + nn) * 16 + l15;
                float cw = C2s[col];
#pragma unroll
                for (int mg = 0; mg < 4; ++mg)
#pragma unroll
                    for (int r = 0; r < 4; ++r)
                        part[mg][r] += fmaxf(acc[mg][nn][r] + c1v[nn], 0.f) * cw;
            }
#pragma unroll
            for (int off = 1; off < 16; off <<= 1)
#pragma unroll
                for (int mg = 0; mg < 4; ++mg)
#pragma unroll
                    for (int r = 0; r < 4; ++r)
                        part[mg][r] += __shfl_xor(part[mg][r], off, 64);
            if (l15 == 0) {
#pragma unroll
                for (int mg = 0; mg < 4; ++mg)
#pragma unroll
                    for (int r = 0; r < 4; ++r)
                        pLds[wv][mg * 16 + quad * 4 + r] = part[mg][r];
            }
        }

        // ---- commit prefetched A into Abuf[nxt] ----
        if (hasNext) {
            unsigned short* dstRow = &Abuf[nxt][myRow * 128];
            const int rot = (myRow & 15) << 3;
            if (rIdxN >= 0) {
#pragma unroll
                for (int i = 0; i < 8; ++i) {
                    int col = (q4 * 32 + i * 4 + rot) & 127;
                    ushort4 o;
                    o.x = f2bf(pf[i].x); o.y = f2bf(pf[i].y);
                    o.z = f2bf(pf[i].z); o.w = f2bf(pf[i].w);
                    *(ushort4*)(dstRow + col) = o;
                }
            } else {
#pragma unroll
                for (int i = 0; i < 8; ++i) {
                    int col = (q4 * 32 + i * 4 + rot) & 127;
                    *(ushort4*)(dstRow + col) = ushort4{0, 0, 0, 0};
                }
            }
            if (q4 == 0) scoreLds[nxt][myRow] = (rIdxN >= 0) ? scN : 0.f;
        }

        // stash epilogue-3 inputs in regs BEFORE the barrier (avoids race with next
        // iteration's gIdxLds[nxt] write, which targets this slot)
        int eg = -1;
        float esc = 0.f;
        if (t < 64) { eg = gIdxLds[cur][t]; esc = scoreLds[cur][t]; }
        rIdxN = rIdxN2;
        __syncthreads();

        // ---- epilogue 3: cross-wave sum, sigmoid, min, store (wave 0 only) ----
        if (t < 64 && eg >= 0) {
            float tot = pLds[0][t] + pLds[1][t] + pLds[2][t] + pLds[3][t] + c2s;
            float cls = 1.f / (1.f + expf(-tot));
            out_score[eg] = fminf(esc, cls);
        }
    }
}

extern "C" void kernel_launch(void* const* d_in, const int* in_sizes, int n_in,
                              void* d_out, int out_size, void* d_ws, size_t ws_size,
                              hipStream_t stream) {
    const float* states = (const float*)d_in[0];
    const float* scores = (const float*)d_in[1];
    const int*   type_ids = (const int*)d_in[2];
    const float* tm = (const float*)d_in[3];
    const float* W1 = (const float*)d_in[4];
    const float* b1 = (const float*)d_in[5];
    const float* W2 = (const float*)d_in[6];
    const float* b2 = (const float*)d_in[7];
    const float* C1 = (const float*)d_in[8];
    const float* c1 = (const float*)d_in[9];
    const float* C2 = (const float*)d_in[10];
    const float* c2 = (const float*)d_in[11];

    char* ws = (char*)d_ws;
    int*   counts  = (int*)(ws + 0);                        // 4 ints
    int*   buckets = (int*)(ws + 4096);                     // 4 * 65536 ints = 1 MB
    unsigned short* wbf = (unsigned short*)(ws + 1052672);  // 12 * 16384 bf16 (frag-linear)

    float* out_state = (float*)d_out;                       // N*128
    float* out_score = out_state + (size_t)Nn * 128;        // N
    float* out_prob  = out_score + Nn;                      // N

    hipMemsetAsync(counts, 0, 16, stream);
    k_prep<<<160, 256, 0, stream>>>(type_ids, tm, W1, W2, C1, counts, buckets, wbf, out_prob);
    k_main<<<dim3(128, 4), 256, 0, stream>>>(states, scores, b1, b2, c1,
        tm, C2, c2, counts, buckets, wbf, out_state, out_score);
}